// Round 1
// baseline (113.587 us; speedup 1.0000x reference)
//
#include <hip/hip_runtime.h>
#include <stdint.h>

// GINConv1d: B=4, N=8192, K=16, C_IN=C_OUT=128
// Single-kernel, ZERO-workspace version: the 256 MiB d_ws poison fills
// (~45 us each, visible as fillBufferAligned in rocprof) appear to sit in the
// timed window; dropping all workspace usage removes the bf16 prepass and the
// poison dependency. Gather is done in fp32 straight from x (per-XCD batch
// pinning keeps each batch's 4 MiB x L2-resident); h is converted to bf16 once
// for the MFMA.
#define BATCH   4
#define NNODE   8192
#define KNBR    16
#define CIN     128
#define COUT    128
#define MB      32          // rows (nodes) per block -> 1024 blocks
#define THREADS 256
#define HS_STRIDE 136       // shorts per h_s row: 128 + 8 pad -> 272B stride

typedef __attribute__((ext_vector_type(8))) short short8;   // 8 bf16 (MFMA A/B frag)
typedef __attribute__((ext_vector_type(4))) float f32x4;

__device__ __forceinline__ short bf16_rne(float f) {
    union { float f; uint32_t u; } v; v.f = f;
    return (short)((v.u + 0x7FFFu + ((v.u >> 16) & 1u)) >> 16);  // round-to-nearest-even
}

// ---------------- fused gather + eps-residual + MFMA GEMM + bias + ReLU ------------
// launch_bounds(256,2): VGPR cap 256; gather prefetch runs in 2 rounds of 8
// neighbors (8 x 16 fp32 regs = 128 VGPRs in flight) for memory-level parallelism.
__global__ __launch_bounds__(THREADS, 2)
void gin_fused_f32(const float*  __restrict__ x,      // [B,N,CIN] fp32
                   const int*    __restrict__ eidx,   // [2,B,N,K] int32; plane 0 = source idx
                   const float*  __restrict__ W,      // [COUT,CIN] fp32
                   const float*  __restrict__ bias,   // [COUT] fp32
                   const float*  __restrict__ epsp,   // [1] fp32
                   float*        __restrict__ out)    // [B,N,COUT] fp32
{
    __shared__ __align__(16) short h_s[MB * HS_STRIDE];

    const int tid = threadIdx.x;
    // XCD-locality swizzle: blockIdx -> XCD round-robin (i & 7). Pin batch b to
    // XCDs {2b,2b+1} so each XCD's gather set = one batch (4 MiB fp32) -> L2-resident.
    const int i   = blockIdx.x;            // 0..1023
    const int xcd = i & 7;
    const int sub = i >> 3;                // 0..127
    const int b   = xcd >> 1;              // batch 0..3
    const int wbi = ((xcd & 1) << 7) | sub;// 0..255 within batch
    const int n0  = wbi * MB;
    const int row0 = b * NNODE + n0;

    const float eps1 = 1.0f + epsp[0];

    // ---------------- Phase A: fp32 gather + sum -> h_s (bf16) ---------------------
    {
        const int r  = tid >> 3;           // row within block, 0..31
        const int q  = tid & 7;            // channel slice, 16 ch each
        const int n  = n0 + r;
        const int c0 = q * 16;
        const int* ip = eidx + ((size_t)b * NNODE + n) * KNBR;   // plane 0

        int js[KNBR];
        #pragma unroll
        for (int p = 0; p < 4; ++p) {
            int4 jv = *(const int4*)(ip + p * 4);
            js[p*4+0]=jv.x; js[p*4+1]=jv.y; js[p*4+2]=jv.z; js[p*4+3]=jv.w;
        }

        const float* xbb = x + (size_t)b * NNODE * CIN;
        const float* xs  = xbb + (size_t)n * CIN + c0;

        float acc[16];
        #pragma unroll
        for (int p = 0; p < 4; ++p) {
            f32x4 v = *(const f32x4*)(xs + p * 4);
            acc[p*4+0]=eps1*v[0]; acc[p*4+1]=eps1*v[1];
            acc[p*4+2]=eps1*v[2]; acc[p*4+3]=eps1*v[3];
        }

        // Two rounds of 8-neighbor prefetch: 32 x 16B loads in flight per thread
        // per round, fully unrolled so t[][] stays in registers (no scratch).
        #pragma unroll
        for (int h = 0; h < 2; ++h) {
            f32x4 t[8][4];
            #pragma unroll
            for (int k = 0; k < 8; ++k) {
                const float* xn = xbb + (size_t)js[h*8+k] * CIN + c0;
                #pragma unroll
                for (int p = 0; p < 4; ++p) t[k][p] = *(const f32x4*)(xn + p * 4);
            }
            #pragma unroll
            for (int k = 0; k < 8; ++k) {
                #pragma unroll
                for (int p = 0; p < 4; ++p) {
                    acc[p*4+0] += t[k][p][0]; acc[p*4+1] += t[k][p][1];
                    acc[p*4+2] += t[k][p][2]; acc[p*4+3] += t[k][p][3];
                }
            }
        }

        short* hp = h_s + r * HS_STRIDE + c0;
        #pragma unroll
        for (int p = 0; p < 2; ++p) {
            short8 s;
            #pragma unroll
            for (int e = 0; e < 8; ++e) s[e] = bf16_rne(acc[p*8+e]);
            *(short8*)(hp + p * 8) = s;
        }
    }

    // ---------------- W -> bf16 B-fragments in registers (per-wave 32-out slice) ---
    const int wave = tid >> 6;
    const int lane = tid & 63;
    const int l16  = lane & 15;
    const int lq   = lane >> 4;            // quad 0..3

    short8 bfrag[2][4];                    // [o_tile][kb]: B[k][n]=W[o][c], n=l16, k=lq*8+j
    #pragma unroll
    for (int t = 0; t < 2; ++t) {
        const float* wp = W + (size_t)(wave * 32 + t * 16 + l16) * CIN;
        #pragma unroll
        for (int kb = 0; kb < 4; ++kb) {
            const float* wq = wp + kb * 32 + lq * 8;
            f32x4 f0 = *(const f32x4*)(wq);
            f32x4 f1 = *(const f32x4*)(wq + 4);
            short8 s;
            s[0]=bf16_rne(f0[0]); s[1]=bf16_rne(f0[1]); s[2]=bf16_rne(f0[2]); s[3]=bf16_rne(f0[3]);
            s[4]=bf16_rne(f1[0]); s[5]=bf16_rne(f1[1]); s[6]=bf16_rne(f1[2]); s[7]=bf16_rne(f1[3]);
            bfrag[t][kb] = s;
        }
    }
    const float bias0 = bias[wave * 32 + l16];
    const float bias1 = bias[wave * 32 + 16 + l16];

    __syncthreads();

    // ---------------- Phase B: MFMA GEMM + bias + ReLU -----------------------------
    float* outb = out + (size_t)row0 * COUT;
    #pragma unroll
    for (int rt = 0; rt < MB / 16; ++rt) {
        const short* ap = h_s + (rt * 16 + l16) * HS_STRIDE + lq * 8;
        short8 afrag[4];
        #pragma unroll
        for (int kb = 0; kb < 4; ++kb)
            afrag[kb] = *(const short8*)(ap + kb * 32);

        #pragma unroll
        for (int t = 0; t < 2; ++t) {
            f32x4 acc = { 0.f, 0.f, 0.f, 0.f };
            #pragma unroll
            for (int kb = 0; kb < 4; ++kb)
                acc = __builtin_amdgcn_mfma_f32_16x16x32_bf16(afrag[kb], bfrag[t][kb], acc, 0, 0, 0);

            const float bv  = t ? bias1 : bias0;
            const int   col = wave * 32 + t * 16 + l16;
            #pragma unroll
            for (int ii = 0; ii < 4; ++ii) {
                const int row = rt * 16 + lq * 4 + ii;   // C/D: row = quad*4 + reg
                float v = acc[ii] + bv;
                outb[(size_t)row * COUT + col] = v > 0.f ? v : 0.f;
            }
        }
    }
}

extern "C" void kernel_launch(void* const* d_in, const int* in_sizes, int n_in,
                              void* d_out, int out_size, void* d_ws, size_t ws_size,
                              hipStream_t stream) {
    const float* x    = (const float*)d_in[0];
    const int*   eidx = (const int*)d_in[1];
    const float* W    = (const float*)d_in[2];
    const float* bias = (const float*)d_in[3];
    const float* eps  = (const float*)d_in[4];
    float*       out  = (float*)d_out;

    (void)d_ws; (void)ws_size;  // deliberately unused: avoid workspace poison-fill cost

    dim3 grid((BATCH * NNODE) / MB);   // 1024 blocks
    gin_fused_f32<<<grid, dim3(THREADS), 0, stream>>>(x, eidx, W, bias, eps, out);
}

// Round 2
// 101.722 us; speedup vs baseline: 1.1166x; 1.1166x over previous
//
#include <hip/hip_runtime.h>
#include <stdint.h>

// GINConv1d: B=4, N=8192, K=16, C_IN=C_OUT=128
//
// Round-1 findings: d_ws poison fills are UNCONDITIONAL (appear even with ws
// unused) -> using the workspace is free. fp32 gather (44 us, VGPR=56, occ 29%,
// 13% HBM) is gather-latency-bound: L2 working set doubled vs bf16 (4 MiB/XCD
// thrashes) and the compiler collapsed the prefetch to ~4 loads in flight.
//
// This version: bf16 staging restored + latency attack:
//  - MB=16, one thread per (node, 8ch): 16 neighbor loads of one short8 each
//    (64 data VGPRs), sched_barrier(0) forces all 16 in flight before any add.
//  - W fragments loaded AFTER the gather -> peak VGPR <= 128 ->
//    __launch_bounds__(256,4) = 4 waves/SIMD (2x round-0 occupancy).
//  - nontemporal out stores: 16 MB output stream must not evict the 2 MiB/XCD
//    bf16 x tile from L2.
#define BATCH   4
#define NNODE   8192
#define KNBR    16
#define CIN     128
#define COUT    128
#define MB      16          // rows (nodes) per block -> 2048 blocks
#define THREADS 256
#define HS_STRIDE 136       // shorts per h_s row: 128 + 8 pad

typedef __attribute__((ext_vector_type(8))) short short8;   // 8 bf16 (MFMA A/B frag)
typedef __attribute__((ext_vector_type(4))) float f32x4;

__device__ __forceinline__ short bf16_rne(float f) {
    union { float f; uint32_t u; } v; v.f = f;
    return (short)((v.u + 0x7FFFu + ((v.u >> 16) & 1u)) >> 16);  // round-to-nearest-even
}
__device__ __forceinline__ float bf16_f32(short s) {
    union { uint32_t u; float f; } v; v.u = ((uint32_t)(uint16_t)s) << 16;
    return v.f;
}

// ---------------- prepass: x fp32 -> bf16 in workspace -----------------------------
__global__ __launch_bounds__(256)
void cvt_bf16(const float* __restrict__ x, ushort* __restrict__ xb) {
    const int gid = blockIdx.x * 256 + threadIdx.x;       // 8 elements per thread
    const f32x4* xp = (const f32x4*)x + (size_t)gid * 2;
    f32x4 a = __builtin_nontemporal_load(xp);             // x is dead after this
    f32x4 c = __builtin_nontemporal_load(xp + 1);
    short8 s;
    s[0]=bf16_rne(a[0]); s[1]=bf16_rne(a[1]); s[2]=bf16_rne(a[2]); s[3]=bf16_rne(a[3]);
    s[4]=bf16_rne(c[0]); s[5]=bf16_rne(c[1]); s[6]=bf16_rne(c[2]); s[7]=bf16_rne(c[3]);
    ((short8*)xb)[gid] = s;
}

// ---------------- fused gather + eps-residual + MFMA GEMM + bias + ReLU ------------
template<bool USEBF>
__global__ __launch_bounds__(THREADS, 4)
void gin_fused(const float*  __restrict__ x,      // [B,N,CIN] fp32
               const ushort* __restrict__ xb,     // [B,N,CIN] bf16 (if USEBF)
               const int*    __restrict__ eidx,   // [2,B,N,K] int32; plane 0 = source idx
               const float*  __restrict__ W,      // [COUT,CIN] fp32
               const float*  __restrict__ bias,   // [COUT] fp32
               const float*  __restrict__ epsp,   // [1] fp32
               float*        __restrict__ out)    // [B,N,COUT] fp32
{
    __shared__ __align__(16) short h_s[MB * HS_STRIDE];

    const int tid = threadIdx.x;
    // XCD-locality swizzle: blockIdx -> XCD round-robin (i & 7). Pin batch b to
    // XCDs {2b,2b+1} so each XCD's gather set = one batch (2 MiB bf16) -> L2-resident.
    const int i   = blockIdx.x;            // 0..2047
    const int xcd = i & 7;
    const int sub = i >> 3;                // 0..255
    const int b   = xcd >> 1;              // batch 0..3
    const int wbi = ((xcd & 1) << 8) | sub;// 0..511 within batch
    const int n0  = wbi * MB;
    const int row0 = b * NNODE + n0;

    const float eps1 = 1.0f + epsp[0];

    // ---------------- Phase A: gather + sum -> h_s (bf16) --------------------------
    {
        const int r  = tid >> 4;           // row within block, 0..15
        const int q  = tid & 15;           // channel slice, 8 ch each
        const int n  = n0 + r;
        const int c0 = q * 8;
        const int* ip = eidx + ((size_t)b * NNODE + n) * KNBR;   // plane 0

        int js[KNBR];
        #pragma unroll
        for (int p = 0; p < 4; ++p) {
            int4 jv = *(const int4*)(ip + p * 4);
            js[p*4+0]=jv.x; js[p*4+1]=jv.y; js[p*4+2]=jv.z; js[p*4+3]=jv.w;
        }

        float acc[8];

        if constexpr (USEBF) {
            const ushort* xbb = xb + (size_t)b * NNODE * CIN;
            short8 s0 = *(const short8*)(xbb + (size_t)n * CIN + c0);

            // ALL 16 neighbor slices prefetched (16 x 16B loads in flight per
            // thread). sched_barrier(0) pins the loads BEFORE any accumulation
            // so the compiler cannot collapse them into a load-add chain
            // (round-1 showed it does exactly that: VGPR=56, ~4 loads in flight).
            short8 t[KNBR];
            #pragma unroll
            for (int k = 0; k < KNBR; ++k)
                t[k] = *(const short8*)(xbb + (size_t)js[k] * CIN + c0);
            __builtin_amdgcn_sched_barrier(0);

            #pragma unroll
            for (int e = 0; e < 8; ++e) acc[e] = eps1 * bf16_f32(s0[e]);
            #pragma unroll
            for (int k = 0; k < KNBR; ++k) {
                #pragma unroll
                for (int e = 0; e < 8; ++e) acc[e] += bf16_f32(t[k][e]);
            }
        } else {
            const float* xbb = x + (size_t)b * NNODE * CIN;
            const float* xs  = xbb + (size_t)n * CIN + c0;
            f32x4 v0 = *(const f32x4*)(xs);
            f32x4 v1 = *(const f32x4*)(xs + 4);
            #pragma unroll
            for (int e = 0; e < 4; ++e) { acc[e] = eps1*v0[e]; acc[4+e] = eps1*v1[e]; }
            #pragma unroll
            for (int k = 0; k < KNBR; ++k) {
                const float* xn = xbb + (size_t)js[k] * CIN + c0;
                f32x4 w0 = *(const f32x4*)(xn);
                f32x4 w1 = *(const f32x4*)(xn + 4);
                #pragma unroll
                for (int e = 0; e < 4; ++e) { acc[e] += w0[e]; acc[4+e] += w1[e]; }
            }
        }

        short* hp = h_s + r * HS_STRIDE + c0;
        short8 s;
        #pragma unroll
        for (int e = 0; e < 8; ++e) s[e] = bf16_rne(acc[e]);
        *(short8*)hp = s;
    }

    // ---------------- W -> bf16 B-fragments (AFTER gather: caps peak VGPR) ---------
    const int wave = tid >> 6;
    const int lane = tid & 63;
    const int l16  = lane & 15;
    const int lq   = lane >> 4;            // quad 0..3

    short8 bfrag[2][4];                    // [o_tile][kb]: B[k][n]=W[o][c], n=l16, k=lq*8+j
    #pragma unroll
    for (int t = 0; t < 2; ++t) {
        const float* wp = W + (size_t)(wave * 32 + t * 16 + l16) * CIN;
        #pragma unroll
        for (int kb = 0; kb < 4; ++kb) {
            const float* wq = wp + kb * 32 + lq * 8;
            f32x4 f0 = *(const f32x4*)(wq);
            f32x4 f1 = *(const f32x4*)(wq + 4);
            short8 s;
            s[0]=bf16_rne(f0[0]); s[1]=bf16_rne(f0[1]); s[2]=bf16_rne(f0[2]); s[3]=bf16_rne(f0[3]);
            s[4]=bf16_rne(f1[0]); s[5]=bf16_rne(f1[1]); s[6]=bf16_rne(f1[2]); s[7]=bf16_rne(f1[3]);
            bfrag[t][kb] = s;
        }
    }
    const float bias0 = bias[wave * 32 + l16];
    const float bias1 = bias[wave * 32 + 16 + l16];

    __syncthreads();

    // ---------------- Phase B: MFMA GEMM + bias + ReLU -----------------------------
    float* outb = out + (size_t)row0 * COUT;
    {
        const short* ap = h_s + l16 * HS_STRIDE + lq * 8;
        short8 afrag[4];
        #pragma unroll
        for (int kb = 0; kb < 4; ++kb)
            afrag[kb] = *(const short8*)(ap + kb * 32);

        #pragma unroll
        for (int t = 0; t < 2; ++t) {
            f32x4 acc = { 0.f, 0.f, 0.f, 0.f };
            #pragma unroll
            for (int kb = 0; kb < 4; ++kb)
                acc = __builtin_amdgcn_mfma_f32_16x16x32_bf16(afrag[kb], bfrag[t][kb], acc, 0, 0, 0);

            const float bv  = t ? bias1 : bias0;
            const int   col = wave * 32 + t * 16 + l16;
            #pragma unroll
            for (int ii = 0; ii < 4; ++ii) {
                const int row = lq * 4 + ii;             // C/D: row = quad*4 + reg
                float v = acc[ii] + bv;
                v = v > 0.f ? v : 0.f;
                // nt store: don't let the 16 MB out stream evict the bf16 x tile
                __builtin_nontemporal_store(v, &outb[(size_t)row * COUT + col]);
            }
        }
    }
}

extern "C" void kernel_launch(void* const* d_in, const int* in_sizes, int n_in,
                              void* d_out, int out_size, void* d_ws, size_t ws_size,
                              hipStream_t stream) {
    const float* x    = (const float*)d_in[0];
    const int*   eidx = (const int*)d_in[1];
    const float* W    = (const float*)d_in[2];
    const float* bias = (const float*)d_in[3];
    const float* eps  = (const float*)d_in[4];
    float*       out  = (float*)d_out;

    const size_t need = (size_t)BATCH * NNODE * CIN * sizeof(ushort);  // 8 MiB
    dim3 grid((BATCH * NNODE) / MB);   // 2048 blocks

    if (ws_size >= need) {
        ushort* xb = (ushort*)d_ws;
        const int nelem = BATCH * NNODE * CIN;                 // 4 M
        cvt_bf16<<<dim3(nelem / (256 * 8)), dim3(256), 0, stream>>>(x, xb);
        gin_fused<true><<<grid, dim3(THREADS), 0, stream>>>(x, xb, eidx, W, bias, eps, out);
    } else {
        gin_fused<false><<<grid, dim3(THREADS), 0, stream>>>(x, nullptr, eidx, W, bias, eps, out);
    }
}

// Round 4
// 94.960 us; speedup vs baseline: 1.1962x; 1.0712x over previous
//
#include <hip/hip_runtime.h>
#include <stdint.h>

// GINConv1d: B=4, N=8192, K=16, C_IN=C_OUT=128
//
// Round-2 post-mortem: MB=16 + launch_bounds(256,4) + sched_barrier REGRESSED
// (kernel budget ~26 -> ~32 us). Likely VGPR cap 128 caused scratch spills in
// the 16-neighbor prefetch, plus doubled per-block W-convert overhead.
// Round-3: compile fix only (native ext-vector int4 for nontemporal load).
// Structure: round-0 anchor (MB=32, bounds(256,2), dual short8 prefetch) plus:
//  - W pre-converted to bf16 in the prepass (blocks load short8 frags directly:
//    -64 MiB L2 traffic, -130 VALU/thread prologue before the barrier).
//  - nontemporal out stores + eidx loads: the 16 MiB out stream / 2 MiB index
//    read must not evict the 2 MiB/XCD bf16 gather set from L2.
#define BATCH   4
#define NNODE   8192
#define KNBR    16
#define CIN     128
#define COUT    128
#define MB      32          // rows (nodes) per block -> 1024 blocks
#define THREADS 256
#define HS_STRIDE 136       // shorts per h_s row: 128 + 8 pad

#define XELEM   (BATCH * NNODE * CIN)          // 4194304 fp32 elements
#define WELEM   (COUT * CIN)                   // 16384 fp32 elements
#define CVT_XBLK (XELEM / (256 * 8))           // 2048 blocks for x
#define CVT_WBLK (WELEM / (256 * 8))           // 8 blocks for W

typedef __attribute__((ext_vector_type(8))) short short8;   // 8 bf16 (MFMA A/B frag)
typedef __attribute__((ext_vector_type(4))) float f32x4;
typedef __attribute__((ext_vector_type(4))) int   i32x4;    // native vec: ok for nontemporal builtins

__device__ __forceinline__ short bf16_rne(float f) {
    union { float f; uint32_t u; } v; v.f = f;
    return (short)((v.u + 0x7FFFu + ((v.u >> 16) & 1u)) >> 16);  // round-to-nearest-even
}
__device__ __forceinline__ float bf16_f32(short s) {
    union { uint32_t u; float f; } v; v.u = ((uint32_t)(uint16_t)s) << 16;
    return v.f;
}

// ---------------- prepass: {x, W} fp32 -> bf16 in workspace ------------------------
// blocks [0, 2048): x -> xb ;  blocks [2048, 2056): W -> wb (= xb + XELEM)
__global__ __launch_bounds__(256)
void cvt_bf16(const float* __restrict__ x, const float* __restrict__ W,
              ushort* __restrict__ xb) {
    const int bi = blockIdx.x;
    const float* src;
    ushort*      dst;
    int          gid;
    if (bi < CVT_XBLK) { src = x; dst = xb;          gid = bi * 256 + threadIdx.x; }
    else               { src = W; dst = xb + XELEM;  gid = (bi - CVT_XBLK) * 256 + threadIdx.x; }
    const f32x4* xp = (const f32x4*)src + (size_t)gid * 2;
    f32x4 a = __builtin_nontemporal_load(xp);        // fp32 source is dead after this
    f32x4 c = __builtin_nontemporal_load(xp + 1);
    short8 s;
    s[0]=bf16_rne(a[0]); s[1]=bf16_rne(a[1]); s[2]=bf16_rne(a[2]); s[3]=bf16_rne(a[3]);
    s[4]=bf16_rne(c[0]); s[5]=bf16_rne(c[1]); s[6]=bf16_rne(c[2]); s[7]=bf16_rne(c[3]);
    ((short8*)dst)[gid] = s;
}

// ---------------- fused gather + eps-residual + MFMA GEMM + bias + ReLU ------------
// launch_bounds(256,2): VGPR cap 256 so all 32 neighbor prefetch loads (128 data
// VGPRs) stay in flight without spilling (round-2 showed the 128-VGPR cap spills).
template<bool USEBF>
__global__ __launch_bounds__(THREADS, 2)
void gin_fused(const float*  __restrict__ x,      // [B,N,CIN] fp32
               const ushort* __restrict__ xb,     // [B,N,CIN] bf16 (if USEBF)
               const ushort* __restrict__ wb,     // [COUT,CIN] bf16 (if USEBF)
               const int*    __restrict__ eidx,   // [2,B,N,K] int32; plane 0 = source idx
               const float*  __restrict__ W,      // [COUT,CIN] fp32
               const float*  __restrict__ bias,   // [COUT] fp32
               const float*  __restrict__ epsp,   // [1] fp32
               float*        __restrict__ out)    // [B,N,COUT] fp32
{
    __shared__ __align__(16) short h_s[MB * HS_STRIDE];

    const int tid = threadIdx.x;
    // XCD-locality swizzle: blockIdx -> XCD round-robin (i & 7). Pin batch b to
    // XCDs {2b,2b+1} so each XCD's gather set = one batch (2 MiB bf16) -> L2-resident.
    const int i   = blockIdx.x;            // 0..1023
    const int xcd = i & 7;
    const int sub = i >> 3;                // 0..127
    const int b   = xcd >> 1;              // batch 0..3
    const int wbi = ((xcd & 1) << 7) | sub;// 0..255 within batch
    const int n0  = wbi * MB;
    const int row0 = b * NNODE + n0;

    const float eps1 = 1.0f + epsp[0];

    // ---------------- Phase A: gather + sum -> h_s (bf16) --------------------------
    {
        const int r  = tid >> 3;           // row within block, 0..31
        const int q  = tid & 7;            // channel slice, 16 ch each
        const int n  = n0 + r;
        const int c0 = q * 16;
        const int* ip = eidx + ((size_t)b * NNODE + n) * KNBR;   // plane 0

        int js[KNBR];
        #pragma unroll
        for (int p = 0; p < 4; ++p) {
            i32x4 jv = __builtin_nontemporal_load((const i32x4*)(ip + p * 4));
            js[p*4+0]=jv.x; js[p*4+1]=jv.y; js[p*4+2]=jv.z; js[p*4+3]=jv.w;
        }

        float acc[16];

        if constexpr (USEBF) {
            const ushort* xbb = xb + (size_t)b * NNODE * CIN;
            const ushort* xs  = xbb + (size_t)n * CIN + c0;
            short8 s0 = *(const short8*)xs, s1 = *(const short8*)(xs + 8);

            // Prefetch ALL 16 neighbor slices into registers (32 x 16B loads in
            // flight per thread) BEFORE any accumulation -> memory-level parallelism.
            short8 t0[KNBR], t1[KNBR];
            #pragma unroll
            for (int k = 0; k < KNBR; ++k) {
                const ushort* xn = xbb + (size_t)js[k] * CIN + c0;
                t0[k] = *(const short8*)xn;
                t1[k] = *(const short8*)(xn + 8);
            }

            #pragma unroll
            for (int e = 0; e < 8; ++e) {
                acc[e]     = eps1 * bf16_f32(s0[e]);
                acc[8 + e] = eps1 * bf16_f32(s1[e]);
            }
            #pragma unroll
            for (int k = 0; k < KNBR; ++k) {
                #pragma unroll
                for (int e = 0; e < 8; ++e) {
                    acc[e]     += bf16_f32(t0[k][e]);
                    acc[8 + e] += bf16_f32(t1[k][e]);
                }
            }
        } else {
            const float* xbb = x + (size_t)b * NNODE * CIN;
            const float* xs  = xbb + (size_t)n * CIN + c0;
            #pragma unroll
            for (int p = 0; p < 4; ++p) {
                f32x4 v = *(const f32x4*)(xs + p * 4);
                acc[p*4+0]=eps1*v[0]; acc[p*4+1]=eps1*v[1]; acc[p*4+2]=eps1*v[2]; acc[p*4+3]=eps1*v[3];
            }
            #pragma unroll
            for (int k = 0; k < KNBR; ++k) {
                const float* xn = xbb + (size_t)js[k] * CIN + c0;
                #pragma unroll
                for (int p = 0; p < 4; ++p) {
                    f32x4 v = *(const f32x4*)(xn + p * 4);
                    acc[p*4+0]+=v[0]; acc[p*4+1]+=v[1]; acc[p*4+2]+=v[2]; acc[p*4+3]+=v[3];
                }
            }
        }

        short* hp = h_s + r * HS_STRIDE + c0;
        #pragma unroll
        for (int p = 0; p < 2; ++p) {
            short8 s;
            #pragma unroll
            for (int e = 0; e < 8; ++e) s[e] = bf16_rne(acc[p*8+e]);
            *(short8*)(hp + p * 8) = s;
        }
    }

    // ---------------- W -> bf16 B-fragments in registers (per-wave 32-out slice) ---
    const int wave = tid >> 6;
    const int lane = tid & 63;
    const int l16  = lane & 15;
    const int lq   = lane >> 4;            // quad 0..3

    short8 bfrag[2][4];                    // [o_tile][kb]: B[k][n]=W[o][c], n=l16, k=lq*8+j
    if constexpr (USEBF) {
        #pragma unroll
        for (int t = 0; t < 2; ++t) {
            const ushort* wp = wb + (size_t)(wave * 32 + t * 16 + l16) * CIN;
            #pragma unroll
            for (int kb = 0; kb < 4; ++kb)
                bfrag[t][kb] = *(const short8*)(wp + kb * 32 + lq * 8);
        }
    } else {
        #pragma unroll
        for (int t = 0; t < 2; ++t) {
            const float* wp = W + (size_t)(wave * 32 + t * 16 + l16) * CIN;
            #pragma unroll
            for (int kb = 0; kb < 4; ++kb) {
                const float* wq = wp + kb * 32 + lq * 8;
                f32x4 f0 = *(const f32x4*)(wq);
                f32x4 f1 = *(const f32x4*)(wq + 4);
                short8 s;
                s[0]=bf16_rne(f0[0]); s[1]=bf16_rne(f0[1]); s[2]=bf16_rne(f0[2]); s[3]=bf16_rne(f0[3]);
                s[4]=bf16_rne(f1[0]); s[5]=bf16_rne(f1[1]); s[6]=bf16_rne(f1[2]); s[7]=bf16_rne(f1[3]);
                bfrag[t][kb] = s;
            }
        }
    }
    const float bias0 = bias[wave * 32 + l16];
    const float bias1 = bias[wave * 32 + 16 + l16];

    __syncthreads();

    // ---------------- Phase B: MFMA GEMM + bias + ReLU -----------------------------
    float* outb = out + (size_t)row0 * COUT;
    #pragma unroll
    for (int rt = 0; rt < MB / 16; ++rt) {
        const short* ap = h_s + (rt * 16 + l16) * HS_STRIDE + lq * 8;
        short8 afrag[4];
        #pragma unroll
        for (int kb = 0; kb < 4; ++kb)
            afrag[kb] = *(const short8*)(ap + kb * 32);

        #pragma unroll
        for (int t = 0; t < 2; ++t) {
            f32x4 acc = { 0.f, 0.f, 0.f, 0.f };
            #pragma unroll
            for (int kb = 0; kb < 4; ++kb)
                acc = __builtin_amdgcn_mfma_f32_16x16x32_bf16(afrag[kb], bfrag[t][kb], acc, 0, 0, 0);

            const float bv  = t ? bias1 : bias0;
            const int   col = wave * 32 + t * 16 + l16;
            #pragma unroll
            for (int ii = 0; ii < 4; ++ii) {
                const int row = rt * 16 + lq * 4 + ii;   // C/D: row = quad*4 + reg
                float v = acc[ii] + bv;
                v = v > 0.f ? v : 0.f;
                // nt store: the 16 MiB out stream must not evict the bf16 gather set
                __builtin_nontemporal_store(v, &outb[(size_t)row * COUT + col]);
            }
        }
    }
}

extern "C" void kernel_launch(void* const* d_in, const int* in_sizes, int n_in,
                              void* d_out, int out_size, void* d_ws, size_t ws_size,
                              hipStream_t stream) {
    const float* x    = (const float*)d_in[0];
    const int*   eidx = (const int*)d_in[1];
    const float* W    = (const float*)d_in[2];
    const float* bias = (const float*)d_in[3];
    const float* eps  = (const float*)d_in[4];
    float*       out  = (float*)d_out;

    const size_t need = (size_t)(XELEM + WELEM) * sizeof(ushort);  // 8 MiB + 32 KiB
    dim3 grid((BATCH * NNODE) / MB);   // 1024 blocks

    if (ws_size >= need) {
        ushort* xb = (ushort*)d_ws;
        cvt_bf16<<<dim3(CVT_XBLK + CVT_WBLK), dim3(256), 0, stream>>>(x, W, xb);
        gin_fused<true><<<grid, dim3(THREADS), 0, stream>>>(x, xb, xb + XELEM, eidx, W, bias, eps, out);
    } else {
        gin_fused<false><<<grid, dim3(THREADS), 0, stream>>>(x, nullptr, nullptr, eidx, W, bias, eps, out);
    }
}